// Round 17
// baseline (43.570 us; speedup 1.0000x reference)
//
#include <hip/hip_runtime.h>

#define HH 80
#define WW 80
#define IMG (HH * WW)             // 6400
#define NV ((HH - 1) * WW)        // 6320 vertical edge slots
#define NPTS (NV + HH * (WW - 1)) // 12640 edge slots per image
#define NPIX (2 * IMG)            // 12800
#define BIGF 1.0e10f
#define INVC 1.0e7f
#define EPSF 1e-8f
#define QSCALE 131072.0f          // 2^17 fixed point (exact-commutative sums)

#define NSEG 50                   // 256-slot segments per set
#define SEGPAD 64                 // scnt row stride (entries 50..63 zeroed)
#define SETSLOTS (NSEG * 256)     // 12800 slots per set

// k_prep: 200 extraction blocks (one per set,segment) + 50 pixel blocks
#define EXBLOCKS (4 * NSEG)
#define PXBLOCKS 50
#define PREPB (EXBLOCKS + PXBLOCKS)

// k_min: A-groups of 8 segments, B-slices of 2 segments
#define BLK 256
#define AGROUPS 7                 // ceil(50/8)
#define BSLICES 25                // 50/2
#define MAXB 512                  // max B points per slice (2 segs x 256)

typedef float f32x2 __attribute__((ext_vector_type(2)));

__device__ __forceinline__ long long wave_reduce_ll(long long v) {
#pragma unroll
  for (int o = 32; o > 0; o >>= 1) {
    int2 p = *(int2*)&v;
    p.x = __shfl_down(p.x, o, 64);
    p.y = __shfl_down(p.y, o, 64);
    v += *(long long*)&p;
  }
  return v;
}

// --------------------------------------------------------------- k_prep
// 250 blocks, NO global atomics, nothing pre-zeroed.
// Blocks 0..199: segment-local compaction (deterministic LDS scan) ->
//   pts[set][seg][0..cnt), scnt[set][seg] plain store, minarr BIGF init.
//   seg==0 blocks also zero scnt entries 50..63 (read-padded by k_min).
// Blocks 200..249: pixel-loss int64 partials, plain stores; first pixel
//   block zeros k_fin's scalar words (consumed only after kernel boundary).
__global__ void __launch_bounds__(256) k_prep(
    const float* __restrict__ pred, const float* __restrict__ gt,
    float2* __restrict__ pts, float* __restrict__ minarr,
    int* __restrict__ scnt, unsigned int* __restrict__ zwords,
    unsigned long long* __restrict__ pixpart) {
  __shared__ int wc[4], wo[4];
  __shared__ long long rl[4];
  int tid = threadIdx.x, lane = tid & 63, wid = tid >> 6;
  int b = blockIdx.x;

  if (b < EXBLOCKS) {
    int set = b / NSEG, seg = b % NSEG;
    minarr[set * SETSLOTS + seg * 256 + tid] = BIGF;
    if (seg == 0 && tid >= NSEG && tid < SEGPAD) scnt[set * SEGPAD + tid] = 0;

    int idx = seg * 256 + tid;   // slot in [0, 12800)
    const float* s = (set < 2 ? pred : gt) + (set & 1) * IMG;
    float r = 0.f, c = 0.f;
    bool valid = false;
    if (idx < NPTS) {
      if (idx < NV) {
        int i = idx / WW, j = idx - i * WW;
        float v1 = s[i * WW + j], v2 = s[(i + 1) * WW + j];
        c = (float)j;
        if (v1 == 0.f)      { r = (float)i;       valid = true; }
        else if (v2 == 0.f) { r = (float)i + 1.f; valid = true; }
        else {
          r = (float)i + fabsf(v1) / (fabsf(v1) + fabsf(v2) + EPSF);
          valid = (v1 * v2 < 0.f);
        }
      } else {
        int t = idx - NV;
        int i = t / (WW - 1), j = t - i * (WW - 1);
        float h1 = s[i * WW + j], h2 = s[i * WW + j + 1];
        r = (float)i;
        if (h1 == 0.f)      { c = (float)j;       valid = true; }
        else if (h2 == 0.f) { c = (float)j + 1.f; valid = true; }
        else {
          c = (float)j + fabsf(h1) / (fabsf(h1) + fabsf(h2) + EPSF);
          valid = (h1 * h2 < 0.f);
        }
      }
    }
    unsigned long long mask = __ballot(valid);
    int nw = __popcll(mask);
    if (lane == 0) wc[wid] = nw;
    __syncthreads();
    if (tid == 0) {
      int t0 = wc[0], t1 = wc[1], t2 = wc[2], t3 = wc[3];
      wo[0] = 0; wo[1] = t0; wo[2] = t0 + t1; wo[3] = t0 + t1 + t2;
      scnt[set * SEGPAD + seg] = t0 + t1 + t2 + t3;
    }
    __syncthreads();
    if (valid) {
      int lpos = __popcll(mask & ((1ull << lane) - 1ull));
      pts[(set * NSEG + seg) * 256 + wo[wid] + lpos] = make_float2(r, c);
    }
  } else {
    int pb = b - EXBLOCKS;
    if (pb == 0 && tid < 16) zwords[tid] = 0u;  // ticket, cnttot[4], sum_i[4]
    int p = pb * 256 + tid;
    float d = fabsf(pred[p] - gt[p]);
    long long q = (long long)(d * QSCALE + 0.5f);
    q = wave_reduce_ll(q);
    if (lane == 0) rl[wid] = q;
    __syncthreads();
    if (tid == 0)
      pixpart[pb] = (unsigned long long)(rl[0] + rl[1] + rl[2] + rl[3]);
  }
}

// --------------------------------------------------------------- k_min core
// Dense A via in-register bucketing over 8 segment counts (named scalars,
// all compile-time indexing). APT chosen block-uniformly: 4 if total<=1024.
template <int APT>
__device__ __forceinline__ void min_core(
    int tid, int sn, int T,
    int m1, int m2, int m3, int m4, int m5, int m6, int m7,
    int segbase, int Aset,
    const float2* __restrict__ pts, float* __restrict__ minarr,
    const f32x2* qx_s, const f32x2* qy_s, const f32x2* q2_s) {
  f32x2 nxv[APT], nyv[APT];
  float p2v[APT], m[APT];
  int slot[APT];
#pragma unroll
  for (int i = 0; i < APT; ++i) {
    int d = tid + i * 256;
    int k = 0, base = 0;
    if (d >= m1) { k = 1; base = m1; }
    if (d >= m2) { k = 2; base = m2; }
    if (d >= m3) { k = 3; base = m3; }
    if (d >= m4) { k = 4; base = m4; }
    if (d >= m5) { k = 5; base = m5; }
    if (d >= m6) { k = 6; base = m6; }
    if (d >= m7) { k = 7; base = m7; }
    bool valid = d < T;
    int pos = d - base;
    float2 p = valid ? pts[(Aset * NSEG + segbase + k) * 256 + pos]
                     : make_float2(0.f, 0.f);
    float nx = -2.f * p.x, ny = -2.f * p.y;
    nxv[i].x = nx; nxv[i].y = nx;
    nyv[i].x = ny; nyv[i].y = ny;
    p2v[i] = fmaf(p.x, p.x, p.y * p.y);
    m[i] = 3.0e38f;
    slot[i] = valid ? (Aset * SETSLOTS + (segbase + k) * 256 + pos) : -1;
  }

  int np2 = sn >> 1;
#pragma unroll 2
  for (int p = 0; p < np2; ++p) {
    f32x2 qx = qx_s[p], qy = qy_s[p], q2 = q2_s[p];
#pragma unroll
    for (int i = 0; i < APT; ++i) {
      f32x2 u = __builtin_elementwise_fma(
          nyv[i], qy, __builtin_elementwise_fma(nxv[i], qx, q2));
      m[i] = fminf(fminf(u.x, u.y), m[i]);   // -> v_min3_f32
    }
  }

#pragma unroll
  for (int i = 0; i < APT; ++i) {
    if (slot[i] >= 0) {
      float d2 = fmaxf(m[i] + p2v[i], 0.f);
      unsigned int mine = __float_as_uint(d2);
      unsigned int* addr = (unsigned int*)&minarr[slot[i]];
      unsigned int cur = __hip_atomic_load(addr, __ATOMIC_RELAXED,
                                           __HIP_MEMORY_SCOPE_AGENT);
      // non-negative floats order as uint bit patterns; min is order-exact
      if (mine < cur) atomicMin(addr, mine);
    }
  }
}

// --------------------------------------------------------------- k_min
// dir 0: A=0 B=2 | 1: A=2 B=0 | 2: A=1 B=3 | 3: A=3 B=1
// grid (7 A-groups, 25 B-slices, 4 dirs) = 700 blocks, all uniform work.
__global__ void __launch_bounds__(BLK) k_min(
    const float2* __restrict__ pts, float* __restrict__ minarr,
    const int* __restrict__ scnt) {
  __shared__ f32x2 qx_s[MAXB / 2 + 1], qy_s[MAXB / 2 + 1], q2_s[MAXB / 2 + 1];
  int tid = threadIdx.x;
  int dir = blockIdx.z;
  int Aset = ((dir & 1) << 1) | (dir >> 1);
  int Bset = Aset ^ 2;

  // stage B: two segments, dense into LDS (SoA triples)
  int seg0 = blockIdx.y * 2;
  int cb0 = scnt[Bset * SEGPAD + seg0];
  int cb1 = scnt[Bset * SEGPAD + seg0 + 1];
  const float2* bp0 = pts + (Bset * NSEG + seg0) * 256;
  if (tid < cb0) {
    float2 q = bp0[tid];
    ((float*)qx_s)[tid] = q.x;
    ((float*)qy_s)[tid] = q.y;
    ((float*)q2_s)[tid] = fmaf(q.x, q.x, q.y * q.y);
  }
  if (tid < cb1) {
    float2 q = bp0[256 + tid];
    ((float*)qx_s)[cb0 + tid] = q.x;
    ((float*)qy_s)[cb0 + tid] = q.y;
    ((float*)q2_s)[cb0 + tid] = fmaf(q.x, q.x, q.y * q.y);
  }
  int nb = cb0 + cb1;
  if ((nb & 1) && tid == 0) {   // pad to even with a far dummy point
    ((float*)qx_s)[nb] = INVC;
    ((float*)qy_s)[nb] = INVC;
    ((float*)q2_s)[nb] = fmaf(INVC, INVC, INVC * INVC);
  }
  int sn = (nb + 1) & ~1;
  __syncthreads();

  // A cumulative counts (block-uniform -> SGPRs)
  int segbase = blockIdx.x * 8;
  const int* ac = scnt + Aset * SEGPAD + segbase;   // entries 50..55 are zeroed
  int a0 = ac[0], a1 = ac[1], a2 = ac[2], a3 = ac[3];
  int a4 = ac[4], a5 = ac[5], a6 = ac[6], a7 = ac[7];
  int m1 = a0, m2 = m1 + a1, m3 = m2 + a2, m4 = m3 + a3;
  int m5 = m4 + a4, m6 = m5 + a5, m7 = m6 + a6;
  int T = m7 + a7;
  if (T == 0 || nb == 0) return;

  if (T <= 1024)
    min_core<4>(tid, sn, T, m1, m2, m3, m4, m5, m6, m7, segbase, Aset,
                pts, minarr, qx_s, qy_s, q2_s);
  else
    min_core<8>(tid, sn, T, m1, m2, m3, m4, m5, m6, m7, segbase, Aset,
                pts, minarr, qx_s, qy_s, q2_s);
}

// --------------------------------------------------------------- k_fin
// 16 blocks (4 per set): per-segment strided slot sums (validity tid<cnt),
// exact int64, device atomicAdd + 16-fence ticket combine (proven cheap).
__global__ void __launch_bounds__(256) k_fin(
    const float* __restrict__ minarr, const int* __restrict__ scnt,
    const unsigned long long* __restrict__ pixpart,
    unsigned int* __restrict__ ticket, unsigned int* __restrict__ cnttot,
    unsigned long long* __restrict__ sum_i, float* __restrict__ out) {
  __shared__ long long rls[4];
  __shared__ long long pix_s;
  int set = blockIdx.x >> 2, q = blockIdx.x & 3;
  int tid = threadIdx.x, lane = tid & 63, wid = tid >> 6;

  // parallel pixel partial sum (every block; only the ticket winner uses it)
  if (wid == 0) {
    long long pv = (lane < PXBLOCKS) ? (long long)pixpart[lane] : 0ll;
    pv = wave_reduce_ll(pv);
    if (lane == 0) pix_s = pv;
  }

  long long ls = 0;
  int csum = 0;
  for (int seg = q; seg < NSEG; seg += 4) {
    int c = scnt[set * SEGPAD + seg];
    csum += c;
    if (tid < c) {
      float d2 = minarr[set * SETSLOTS + seg * 256 + tid];
      ls += (long long)(sqrtf(d2) * QSCALE + 0.5f);
    }
  }
  ls = wave_reduce_ll(ls);
  if (lane == 0) rls[wid] = ls;
  __syncthreads();

  if (tid == 0) {
    long long tot = rls[0] + rls[1] + rls[2] + rls[3];
    atomicAdd(&sum_i[set], (unsigned long long)tot);
    atomicAdd(&cnttot[set], (unsigned int)csum);
    __threadfence();
    unsigned int t = atomicAdd(ticket, 1u);
    if (t == 15u) {  // all 16 blocks' adds complete (device-scope atomics)
      const float iq = 1.0f / QSCALE;
      float ss[4], nn[4];
      for (int k = 0; k < 4; ++k) {
        ss[k] = (float)((long long)atomicAdd(&sum_i[k], 0ull)) * iq;
        nn[k] = fmaxf((float)atomicAdd(&cnttot[k], 0u), 1.f);
      }
      float ch0 = -ss[0] / nn[0] + ss[2] / nn[2];
      float ch1 = -ss[1] / nn[1] + ss[3] / nn[3];
      out[0] = (float)pix_s * iq / (float)NPIX;
      out[1] = 0.5f * (ch0 + ch1);
    }
  }
}

extern "C" void kernel_launch(void* const* d_in, const int* in_sizes, int n_in,
                              void* d_out, int out_size, void* d_ws, size_t ws_size,
                              hipStream_t stream) {
  const float* pred = (const float*)d_in[0];
  const float* gt   = (const float*)d_in[1];
  float* out = (float*)d_out;

  // ws: scnt int[4][64] @0 | zwords u32[16] @1024 (ticket, cnttot[4], pad,
  //     sum_i[4] @1056) | pixpart u64[50] @1152 | pts float2[4][50][256]
  //     @2048 | minarr float[4][12800] after pts. No pre-zeroing kernel:
  //     k_prep writes everything it or its consumers read.
  int* scnt = (int*)d_ws;
  unsigned int* zwords = (unsigned int*)((char*)d_ws + 1024);
  unsigned int* ticket = zwords;            // @1024
  unsigned int* cnttot = zwords + 1;        // @1028..1043
  unsigned long long* sum_i = (unsigned long long*)((char*)d_ws + 1056);
  unsigned long long* pixpart = (unsigned long long*)((char*)d_ws + 1152);
  float2* pts = (float2*)((char*)d_ws + 2048);
  float* minarr = (float*)((char*)d_ws + 2048 + sizeof(float2) * 4 * SETSLOTS);

  k_prep<<<PREPB, 256, 0, stream>>>(pred, gt, pts, minarr, scnt, zwords, pixpart);
  k_min<<<dim3(AGROUPS, BSLICES, 4), BLK, 0, stream>>>(pts, minarr, scnt);
  k_fin<<<16, 256, 0, stream>>>(minarr, scnt, pixpart, ticket, cnttot, sum_i, out);
}

// Round 18
// 40.323 us; speedup vs baseline: 1.0805x; 1.0805x over previous
//
#include <hip/hip_runtime.h>

#define HH 80
#define WW 80
#define IMG (HH * WW)             // 6400
#define NV ((HH - 1) * WW)        // 6320 vertical edge slots
#define NPTS (NV + HH * (WW - 1)) // 12640 edge slots per image
#define NPIX (2 * IMG)            // 12800
#define BIGF 1.0e10f
#define INVC 1.0e7f
#define EPSF 1e-8f
#define QSCALE 131072.0f          // 2^17 fixed point (exact-commutative sums)

// k_prep geometry: each set padded to 12800 slots = 50 blocks x 256 threads
#define SETPAD 12800
#define SBLOCKS (SETPAD / 256)    // 50 blocks per set
#define EXBLOCKS (4 * SBLOCKS)    // 200 extraction blocks
#define PXBLOCKS (NPIX / 256)     // 50 pixel blocks
#define PREPB (EXBLOCKS + PXBLOCKS) // 250

// k_min geometry (r11-exact tiling; quad-SoA LDS: 3 x ds_read_b128 per 4 B)
#define BLK 256                   // 4 waves
#define APT 8                     // A points per thread
#define ACHUNK (BLK * APT)        // 2048
#define ABLOCKS ((NPTS + ACHUNK - 1) / ACHUNK) // 7 worst case; 4 active
#define NSLICE 32
#define MAXSLICE ((((NPTS + NSLICE - 1) / NSLICE) + 3) & ~3) // 396 (x4 padded)
#define MAXP4 (MAXSLICE / 4)      // 99 f32x4 quads

// scalar ws layout (each contended counter on its own 128-B line)
#define CNT_STRIDE 32             // ints; cnt[set] at d_ws + set*128
#define PIX_OFF 512
#define TICKET_OFF 640
#define SUM_OFF 768               // 4 x u64
#define SCALAR_BYTES 1024

typedef float f32x2 __attribute__((ext_vector_type(2)));
typedef float f32x4 __attribute__((ext_vector_type(4)));

__device__ __forceinline__ long long wave_reduce_ll(long long v) {
#pragma unroll
  for (int o = 32; o > 0; o >>= 1) {
    int2 p = *(int2*)&v;
    p.x = __shfl_down(p.x, o, 64);
    p.y = __shfl_down(p.y, o, 64);
    v += *(long long*)&p;
  }
  return v;
}

// --------------------------------------------------------------- k_zero
__global__ void k_zero(unsigned int* __restrict__ w) {
  w[threadIdx.x] = 0u;   // 256 threads x 4 B = 1024 B (cnt, pix, ticket, sum_i)
}

// --------------------------------------------------------------- k_prep
// 250 blocks. minarr init + (blocks 0..199) zero-crossing extraction with
// block-aggregated atomic append (one atomicAdd per block, counters on
// separate cache lines) + (blocks 200..249) pixel loss in exact int64.
// Append ORDER is non-deterministic, but all consumers are order-invariant
// and exact (multiset min; int64 sums) -> output bitwise stable.
__global__ void __launch_bounds__(256) k_prep(
    const float* __restrict__ pred, const float* __restrict__ gt,
    float2* __restrict__ pts, float* __restrict__ minarr,
    int* __restrict__ cnt, unsigned long long* __restrict__ pix_i) {
  __shared__ int wc[4], wo[4];
  __shared__ long long rl[4];
  int tid = threadIdx.x, lane = tid & 63, wid = tid >> 6;
  int gtid = blockIdx.x * 256 + tid;

  if (gtid < 4 * NPTS) minarr[gtid] = BIGF;

  if (blockIdx.x < EXBLOCKS) {
    int set = blockIdx.x / SBLOCKS;
    int idx = (blockIdx.x % SBLOCKS) * 256 + tid;   // slot in [0, SETPAD)
    const float* s = (set < 2 ? pred : gt) + (set & 1) * IMG;
    float r = 0.f, c = 0.f;
    bool valid = false;
    if (idx < NPTS) {
      if (idx < NV) {
        int i = idx / WW, j = idx - i * WW;
        float v1 = s[i * WW + j], v2 = s[(i + 1) * WW + j];
        c = (float)j;
        if (v1 == 0.f)      { r = (float)i;       valid = true; }
        else if (v2 == 0.f) { r = (float)i + 1.f; valid = true; }
        else {
          r = (float)i + fabsf(v1) / (fabsf(v1) + fabsf(v2) + EPSF);
          valid = (v1 * v2 < 0.f);
        }
      } else {
        int t = idx - NV;
        int i = t / (WW - 1), j = t - i * (WW - 1);
        float h1 = s[i * WW + j], h2 = s[i * WW + j + 1];
        r = (float)i;
        if (h1 == 0.f)      { c = (float)j;       valid = true; }
        else if (h2 == 0.f) { c = (float)j + 1.f; valid = true; }
        else {
          c = (float)j + fabsf(h1) / (fabsf(h1) + fabsf(h2) + EPSF);
          valid = (h1 * h2 < 0.f);
        }
      }
    }
    unsigned long long mask = __ballot(valid);
    int nw = __popcll(mask);
    if (lane == 0) wc[wid] = nw;
    __syncthreads();
    if (tid == 0) {
      int t0 = wc[0], t1 = wc[1], t2 = wc[2], t3 = wc[3];
      int tot = t0 + t1 + t2 + t3;
      int base = tot ? atomicAdd(&cnt[set * CNT_STRIDE], tot) : 0;
      wo[0] = base; wo[1] = base + t0; wo[2] = base + t0 + t1;
      wo[3] = base + t0 + t1 + t2;
    }
    __syncthreads();
    if (valid) {
      int lpos = __popcll(mask & ((1ull << lane) - 1ull));
      pts[set * NPTS + wo[wid] + lpos] = make_float2(r, c);
    }
  } else {
    int p = (blockIdx.x - EXBLOCKS) * 256 + tid;
    float d = fabsf(pred[p] - gt[p]);
    long long q = (long long)(d * QSCALE + 0.5f);
    q = wave_reduce_ll(q);
    if (lane == 0) rl[wid] = q;
    __syncthreads();
    if (tid == 0)
      atomicAdd(pix_i, (unsigned long long)(rl[0] + rl[1] + rl[2] + rl[3]));
  }
}

// --------------------------------------------------------------- k_min
// dir 0: A=0 B=2 | 1: A=2 B=0 | 2: A=1 B=3 | 3: A=3 B=1
// min over b of (q2 - 2px*qx - 2py*qy); +p2 and sqrt are monotone (sqrt in k_fin).
// QUAD-SoA LDS: 3 x ds_read_b128 serve 4 B-points x 8 A = 32 pairs (LDS
// wave-instrs per pair halved vs r11's 3 x b64 per 2 B). VALU per pair
// unchanged: 4 pk_fma + 2 min3 per (A, 4B). TTAS atomicMin epilogue.
__global__ void __launch_bounds__(BLK) k_min(
    const float2* __restrict__ pts, float* __restrict__ minarr,
    const int* __restrict__ cnt) {
  int dir = blockIdx.z;
  int Aset = ((dir & 1) << 1) | (dir >> 1);
  int Bset = Aset ^ 2;
  int cntA = cnt[Aset * CNT_STRIDE], cntB = cnt[Bset * CNT_STRIDE];

  int abase0 = blockIdx.x * ACHUNK;
  if (abase0 >= cntA) return;
  int slicelen = (((cntB + NSLICE - 1) / NSLICE) + 1) & ~1;
  int b0 = blockIdx.y * slicelen;
  if (b0 >= cntB) return;
  int n = min(slicelen, cntB - b0);
  int sn4 = (n + 3) & ~3;  // pad to multiple of 4 with dummy far points

  __shared__ f32x4 qx_s[MAXP4], qy_s[MAXP4], q2_s[MAXP4];
  for (int i = threadIdx.x; i < sn4; i += BLK) {
    float2 q = (i < n) ? pts[Bset * NPTS + b0 + i] : make_float2(INVC, INVC);
    ((float*)qx_s)[i] = q.x;
    ((float*)qy_s)[i] = q.y;
    ((float*)q2_s)[i] = fmaf(q.x, q.x, q.y * q.y);
  }
  __syncthreads();

  int abase = abase0 + threadIdx.x;
  f32x4 nxv[APT], nyv[APT];
  float p2v[APT], m[APT];
#pragma unroll
  for (int i = 0; i < APT; ++i) {
    int a = abase + i * BLK;
    float2 p = (a < cntA) ? pts[Aset * NPTS + a] : make_float2(0.f, 0.f);
    float nx = -2.f * p.x, ny = -2.f * p.y;
    nxv[i].x = nx; nxv[i].y = nx; nxv[i].z = nx; nxv[i].w = nx;
    nyv[i].x = ny; nyv[i].y = ny; nyv[i].z = ny; nyv[i].w = ny;
    p2v[i] = fmaf(p.x, p.x, p.y * p.y);
    m[i] = 3.0e38f;
  }

  int np4 = sn4 >> 2;
#pragma unroll 2
  for (int p = 0; p < np4; ++p) {
    f32x4 qx = qx_s[p], qy = qy_s[p], q2 = q2_s[p];   // 3 x ds_read_b128
#pragma unroll
    for (int i = 0; i < APT; ++i) {
      f32x4 u = __builtin_elementwise_fma(
          nyv[i], qy, __builtin_elementwise_fma(nxv[i], qx, q2));
      m[i] = fminf(fminf(u.x, u.y), m[i]);   // -> v_min3_f32
      m[i] = fminf(fminf(u.z, u.w), m[i]);   // -> v_min3_f32
    }
  }

#pragma unroll
  for (int i = 0; i < APT; ++i) {
    int a = abase + i * BLK;
    if (a < cntA) {
      float d2 = fmaxf(m[i] + p2v[i], 0.f);
      unsigned int mine = __float_as_uint(d2);
      unsigned int* addr = (unsigned int*)&minarr[Aset * NPTS + a];
      unsigned int cur = __hip_atomic_load(addr, __ATOMIC_RELAXED,
                                           __HIP_MEMORY_SCOPE_AGENT);
      // non-negative floats order as uint bit patterns; min is order-exact
      if (mine < cur) atomicMin(addr, mine);
    }
  }
}

// --------------------------------------------------------------- k_fin
// 16 blocks (4 per set): exact int64 partial sums of round(sqrt(d2)*2^17),
// device-scope atomicAdd (order-independent, bit-exact). Ticketed last block
// combines and writes the two outputs. 16 device fences total = cheap.
__global__ void __launch_bounds__(256) k_fin(
    const float* __restrict__ minarr, const int* __restrict__ cnt,
    const unsigned long long* __restrict__ pix_i,
    unsigned long long* __restrict__ sum_i,
    unsigned int* __restrict__ ticket, float* __restrict__ out) {
  int set = blockIdx.x >> 2, q = blockIdx.x & 3;
  int tid = threadIdx.x, lane = tid & 63;
  int n = cnt[set * CNT_STRIDE];

  long long ls = 0;
  for (int i = q * 256 + tid; i < n; i += 1024) {
    float d = sqrtf(minarr[set * NPTS + i]);
    ls += (long long)(d * QSCALE + 0.5f);
  }
  ls = wave_reduce_ll(ls);
  if (lane == 0) atomicAdd(&sum_i[set], (unsigned long long)ls);
  __syncthreads();

  if (tid == 0) {
    __threadfence();
    unsigned int t = atomicAdd(ticket, 1u);
    if (t == 15u) {  // all 16 blocks' adds complete (device-scope atomics)
      const float iq = 1.0f / QSCALE;
      float ss[4];
      for (int k = 0; k < 4; ++k)
        ss[k] = (float)((long long)atomicAdd(&sum_i[k], 0ull)) * iq;
      float n0 = fmaxf((float)cnt[0 * CNT_STRIDE], 1.f);
      float n1 = fmaxf((float)cnt[1 * CNT_STRIDE], 1.f);
      float n2 = fmaxf((float)cnt[2 * CNT_STRIDE], 1.f);
      float n3 = fmaxf((float)cnt[3 * CNT_STRIDE], 1.f);
      float ch0 = -ss[0] / n0 + ss[2] / n2;
      float ch1 = -ss[1] / n1 + ss[3] / n3;
      out[0] = (float)(long long)(*pix_i) * iq / (float)NPIX;
      out[1] = 0.5f * (ch0 + ch1);
    }
  }
}

extern "C" void kernel_launch(void* const* d_in, const int* in_sizes, int n_in,
                              void* d_out, int out_size, void* d_ws, size_t ws_size,
                              hipStream_t stream) {
  const float* pred = (const float*)d_in[0];
  const float* gt   = (const float*)d_in[1];
  float* out = (float*)d_out;

  // ws: [0..1023] scalars (zeroed by k_zero) | 4*NPTS float2 pts | 4*NPTS float mins
  int* cnt = (int*)d_ws;                                                // lines @0,128,256,384
  unsigned long long* pix_i = (unsigned long long*)((char*)d_ws + PIX_OFF);
  unsigned int* ticket = (unsigned int*)((char*)d_ws + TICKET_OFF);
  unsigned long long* sum_i = (unsigned long long*)((char*)d_ws + SUM_OFF);
  float2* pts   = (float2*)((char*)d_ws + SCALAR_BYTES);
  float* minarr = (float*)((char*)d_ws + SCALAR_BYTES + sizeof(float2) * 4 * NPTS);

  k_zero<<<1, 256, 0, stream>>>((unsigned int*)d_ws);
  k_prep<<<PREPB, 256, 0, stream>>>(pred, gt, pts, minarr, cnt, pix_i);
  k_min<<<dim3(ABLOCKS, NSLICE, 4), BLK, 0, stream>>>(pts, minarr, cnt);
  k_fin<<<16, 256, 0, stream>>>(minarr, cnt, pix_i, sum_i, ticket, out);
}